// Round 9
// baseline (404.906 us; speedup 1.0000x reference)
//
#include <hip/hip_runtime.h>

// VQ: B=16, C=D=256, H=64, W=64, K=1024
#define BB 16
#define CC 256
#define HH 64
#define WW 64
#define KK 1024
#define DD 256
#define HW (HH * WW)
#define TAU 0.0625f

typedef __attribute__((ext_vector_type(8))) short bf16x8;
typedef __attribute__((ext_vector_type(16))) float f32x16;

union Frag { bf16x8 v; unsigned int u[4]; };

// trunc-split 8 floats into bf16 hi/lo fragments (x = hi + lo + O(2^-16 x), Sterbenz-exact lo)
__device__ inline void split8r(const float4 a, const float4 b, Frag& hi, Frag& lo) {
    float f[8] = {a.x, a.y, a.z, a.w, b.x, b.y, b.z, b.w};
    #pragma unroll
    for (int p = 0; p < 4; ++p) {
        const unsigned int b0 = __float_as_uint(f[2 * p]), b1 = __float_as_uint(f[2 * p + 1]);
        const unsigned int h0 = b0 & 0xFFFF0000u, h1 = b1 & 0xFFFF0000u;
        const float r0 = f[2 * p]     - __uint_as_float(h0);
        const float r1 = f[2 * p + 1] - __uint_as_float(h1);
        hi.u[p] = (h0 >> 16) | h1;
        lo.u[p] = (__float_as_uint(r0) >> 16) | (__float_as_uint(r1) & 0xFFFF0000u);
    }
}

// ehalf[k] = 0.5||e_k||^2 (exact fp32); also zeroes the rescue counter.
__global__ __launch_bounds__(256) void vq_enorm_kernel(const float* __restrict__ e,
                                                       float* __restrict__ ehalf,
                                                       int* __restrict__ g_cnt) {
    if (blockIdx.x == 0 && threadIdx.x == 0) *g_cnt = 0;
    const int wave = threadIdx.x >> 6;
    const int lane = threadIdx.x & 63;
    const int k = blockIdx.x * 4 + wave;
    const float4 v = *reinterpret_cast<const float4*>(e + (size_t)k * DD + lane * 4);
    float s = v.x * v.x + v.y * v.y + v.z * v.z + v.w * v.w;
    #pragma unroll
    for (int off = 32; off; off >>= 1) s += __shfl_xor(s, off, 64);
    if (lane == 0) ehalf[k] = 0.5f * s;
}

// Split codebook into bf16 hi/lo, written in MFMA-fragment-linear order:
// elem off = ct*16384 + ks*1024 + term*512 + lane*8 + di,
// where code = ct*32 + (lane&31), dim = ks*16 + (lane>>5)*8 + di.
// A wave's per-k-step B-frag read is then one contiguous 1 KB dwordx4 load.
__global__ __launch_bounds__(256) void vq_split_t_kernel(const float* __restrict__ e,
                                                         unsigned short* __restrict__ ebt) {
    const int tid = threadIdx.x;
    const int code = blockIdx.x * 8 + (tid >> 5);
    const int sub = tid & 31;
    const int ks = sub >> 1, lq = sub & 1;
    const int ct = code >> 5, lc = code & 31;
    const float* src = e + (size_t)code * DD + ks * 16 + lq * 8;
    Frag hi, lo;
    split8r(*reinterpret_cast<const float4*>(src),
            *reinterpret_cast<const float4*>(src + 4), hi, lo);
    unsigned short* dst = ebt + (size_t)ct * 16384 + ks * 1024 + (size_t)(lq * 32 + lc) * 8;
    *reinterpret_cast<bf16x8*>(dst)       = hi.v;   // term 0 (hi)
    *reinterpret_cast<bf16x8*>(dst + 512) = lo.v;   // term 1 (lo)
}

// Main: one block per (b,h) = 64 tokens x all 1024 codes.
// score = x.e - 0.5||e||^2 via 3-term bf16 32x32x16 MFMA.
// A (tokens) in registers; B streamed DIRECTLY from L2/L1 via the transposed
// codebook (coalesced 1 KB/wave loads). No barriers, no asm in the K-loop.
// Wave (mg,ng): tokens mg*32..+31, code-tiles ct = ng*16 + 0..15.
__global__ __launch_bounds__(256, 2) void vq_mfma_kernel(
    const float* __restrict__ in, const float* __restrict__ emb,
    const float* __restrict__ ehalf, const unsigned short* __restrict__ ebt,
    int* __restrict__ g_cnt, int* __restrict__ g_list,
    float* __restrict__ out) {

    __shared__ float x_lds[64][260];
    __shared__ float eh_lds[KK];
    __shared__ float mv[64][2], m2l[64][2];
    __shared__ int   mi[64][2];
    __shared__ int   idx_lds[64];

    const int tid = threadIdx.x;
    const int bid = blockIdx.x;
    const int b = bid >> 6, h = bid & 63;
    const int w = tid & 63, cs = tid >> 6;

    // ---- stage x fp32 (coalesced over w) + eh ----
    {
        const float* src = in + (size_t)b * CC * HW + (size_t)h * WW + w;
        #pragma unroll
        for (int c = cs; c < CC; c += 4) x_lds[w][c] = src[(size_t)c * HW];
        #pragma unroll
        for (int k = tid; k < KK; k += 256) eh_lds[k] = ehalf[k];
    }
    __syncthreads();

    const int lane = tid & 63;
    const int wv = tid >> 6;                 // 4 waves
    const int mg = wv >> 1, ng = wv & 1;
    const int lc = lane & 31, lq = lane >> 5;
    const int trow = mg * 32 + lc;

    // ---- extract A fragments once: 16 k-steps x (hi,lo) = 128 VGPRs ----
    Frag ah[16], al[16];
    #pragma unroll
    for (int ks = 0; ks < 16; ++ks) {
        const float4 v0 = *reinterpret_cast<const float4*>(&x_lds[trow][ks * 16 + lq * 8]);
        const float4 v1 = *reinterpret_cast<const float4*>(&x_lds[trow][ks * 16 + lq * 8 + 4]);
        split8r(v0, v1, ah[ks], al[ks]);
    }

    float bestv[16], best2[16]; int besti[16];
    #pragma unroll
    for (int r = 0; r < 16; ++r) { bestv[r] = -3.4e38f; best2[r] = -3.4e38f; besti[r] = 0; }

    // ---- K-loop: stream B frags from L2, 3 MFMA per k-step, 2 acc chains ----
    #pragma unroll 1
    for (int cti = 0; cti < 16; ++cti) {
        const int ct = ng * 16 + cti;                       // codes ascend with cti
        const unsigned short* bb = ebt + (size_t)ct * 16384 + (size_t)lane * 8;
        const int code = ct * 32 + lc;
        const float nh = -eh_lds[code];
        f32x16 acc_h, acc_l;
        #pragma unroll
        for (int r = 0; r < 16; ++r) { acc_h[r] = nh; acc_l[r] = 0.0f; }
        #pragma unroll
        for (int ks = 0; ks < 16; ++ks) {
            const bf16x8 bh = *reinterpret_cast<const bf16x8*>(bb + ks * 1024);
            const bf16x8 bl = *reinterpret_cast<const bf16x8*>(bb + ks * 1024 + 512);
            acc_h = __builtin_amdgcn_mfma_f32_32x32x16_bf16(ah[ks].v, bh, acc_h, 0, 0, 0);
            acc_l = __builtin_amdgcn_mfma_f32_32x32x16_bf16(al[ks].v, bh, acc_l, 0, 0, 0);
            acc_h = __builtin_amdgcn_mfma_f32_32x32x16_bf16(ah[ks].v, bl, acc_h, 0, 0, 0);
        }
        #pragma unroll
        for (int r = 0; r < 16; ++r) {
            const float v = acc_h[r] + acc_l[r];
            if (v > bestv[r]) { best2[r] = bestv[r]; bestv[r] = v; besti[r] = code; }
            else if (v > best2[r]) best2[r] = v;
        }
    }

    // ---- butterfly across the 32 code-columns ----
    #pragma unroll
    for (int m = 1; m < 32; m <<= 1) {
        #pragma unroll
        for (int r = 0; r < 16; ++r) {
            const float ob = __shfl_xor(bestv[r], m, 64);
            const float o2 = __shfl_xor(best2[r], m, 64);
            const int   oi = __shfl_xor(besti[r], m, 64);
            if (ob > bestv[r] || (ob == bestv[r] && oi < besti[r])) {
                best2[r] = fmaxf(bestv[r], o2); bestv[r] = ob; besti[r] = oi;
            } else {
                best2[r] = fmaxf(best2[r], ob);
            }
        }
    }
    if (lc == 0) {
        #pragma unroll
        for (int r = 0; r < 16; ++r) {
            const int row = mg * 32 + (r & 3) + 8 * (r >> 2) + 4 * lq;  // C/D row map (m74/m101)
            mv[row][ng] = bestv[r]; m2l[row][ng] = best2[r]; mi[row][ng] = besti[r];
        }
    }
    __syncthreads();

    // ---- merge ng halves per token; flag small margins into compact rescue list ----
    if (tid < 64) {
        const float v0 = mv[tid][0], s0 = m2l[tid][0]; const int i0 = mi[tid][0];
        const float v1 = mv[tid][1], s1 = m2l[tid][1]; const int i1 = mi[tid][1];
        float fb, f2; int fi;
        if (v1 > v0 || (v1 == v0 && i1 < i0)) { fb = v1; fi = i1; f2 = fmaxf(v0, s1); }
        else { fb = v0; fi = i0; f2 = fmaxf(s0, v1); }
        idx_lds[tid] = fi;
        if (fb - f2 < TAU) {
            const int p = atomicAdd(g_cnt, 1);
            g_list[p] = (bid << 6) + tid;
        }
    }
    __syncthreads();

    // ---- epilogue: out = x + (q - x), x from intact LDS tile ----
    {
        float* dst = out + (size_t)b * CC * HW + (size_t)h * WW + w;
        const float* erow = emb + (size_t)idx_lds[w] * DD;
        #pragma unroll
        for (int c = cs; c < CC; c += 4) {
            const float x = x_lds[w][c];
            const float q = erow[c];
            dst[(size_t)c * HW] = x + (q - x);
        }
    }
}

// Rescue: flagged tokens recomputed exactly in fp32, strided over blocks (validated r8).
__global__ __launch_bounds__(256) void vq_rescue_kernel(
    const float* __restrict__ in, const float* __restrict__ emb,
    const float* __restrict__ ehalf, const int* __restrict__ g_cnt,
    const int* __restrict__ g_list, float* __restrict__ out) {

    __shared__ float xs[DD];
    __shared__ float rv[4]; __shared__ int ri[4];
    __shared__ int fin;

    const int tid = threadIdx.x;
    const int n = *g_cnt;
    for (int li = blockIdx.x; li < n; li += (int)gridDim.x) {
        const int tok = g_list[li];
        const int b = tok >> 12, h = (tok >> 6) & 63, w = tok & 63;
        xs[tid] = in[(size_t)(b * CC + tid) * HW + h * WW + w];
        __syncthreads();
        float best = -3.4e38f; int bidx = 0;
        #pragma unroll
        for (int cc = 0; cc < 4; ++cc) {
            const int code = tid * 4 + cc;
            float sc = -ehalf[code];
            const float* er = emb + (size_t)code * DD;
            for (int d = 0; d < DD; d += 4) {
                sc = fmaf(xs[d + 0], er[d + 0], sc);
                sc = fmaf(xs[d + 1], er[d + 1], sc);
                sc = fmaf(xs[d + 2], er[d + 2], sc);
                sc = fmaf(xs[d + 3], er[d + 3], sc);
            }
            if (sc > best) { best = sc; bidx = code; }
        }
        #pragma unroll
        for (int m = 1; m < 64; m <<= 1) {
            const float ov = __shfl_xor(best, m, 64);
            const int   oi = __shfl_xor(bidx, m, 64);
            if (ov > best || (ov == best && oi < bidx)) { best = ov; bidx = oi; }
        }
        if ((tid & 63) == 0) { rv[tid >> 6] = best; ri[tid >> 6] = bidx; }
        __syncthreads();
        if (tid == 0) {
            float fb = rv[0]; int fi2 = ri[0];
            #pragma unroll
            for (int q2 = 1; q2 < 4; ++q2)
                if (rv[q2] > fb || (rv[q2] == fb && ri[q2] < fi2)) { fb = rv[q2]; fi2 = ri[q2]; }
            fin = fi2;
        }
        __syncthreads();
        const int fid = fin;
        const float xv = xs[tid];
        const float qv = emb[(size_t)fid * DD + tid];
        out[(size_t)(b * CC + tid) * HW + h * WW + w] = xv + (qv - xv);
        __syncthreads();
    }
}

// Fallback (validated fp32 VALU path) if ws is too small.
__global__ __launch_bounds__(256) void vq_fallback_kernel(
    const float* __restrict__ in, const float* __restrict__ emb,
    const float* __restrict__ ehalf, float* __restrict__ out) {

    __shared__ float x_lds[64][260];
    __shared__ float red_v[64][16];
    __shared__ int   red_i[64][16];
    __shared__ int   idx_lds[64];

    const int tid = threadIdx.x;
    const int bid = blockIdx.x;
    const int b = bid >> 6, h = bid & 63;
    const int w = tid & 63, cs = tid >> 6;
    {
        const float* src = in + (size_t)b * CC * HW + (size_t)h * WW + w;
        #pragma unroll
        for (int c = cs; c < CC; c += 4) x_lds[w][c] = src[(size_t)c * HW];
    }
    __syncthreads();
    const int i = tid & 15;
    const int j = tid >> 4;
    float best_v[4]; int best_i[4];
    #pragma unroll
    for (int t = 0; t < 4; ++t) { best_v[t] = -3.4e38f; best_i[t] = 0; }
    for (int chunk = 0; chunk < KK; chunk += 128) {
        const int c0 = chunk + j * 8;
        const float* e0 = emb + (size_t)c0 * DD;
        float acc[4][8];
        #pragma unroll
        for (int cj = 0; cj < 8; ++cj) {
            const float nh = -ehalf[c0 + cj];
            #pragma unroll
            for (int t = 0; t < 4; ++t) acc[t][cj] = nh;
        }
        #pragma unroll 2
        for (int d = 0; d < DD; d += 4) {
            float4 xv[4], ev[8];
            #pragma unroll
            for (int t = 0; t < 4; ++t)
                xv[t] = *reinterpret_cast<const float4*>(&x_lds[i + 16 * t][d]);
            #pragma unroll
            for (int cj = 0; cj < 8; ++cj)
                ev[cj] = *reinterpret_cast<const float4*>(e0 + (size_t)cj * DD + d);
            #pragma unroll
            for (int t = 0; t < 4; ++t) {
                #pragma unroll
                for (int cj = 0; cj < 8; ++cj) {
                    float a = acc[t][cj];
                    a = fmaf(xv[t].x, ev[cj].x, a);
                    a = fmaf(xv[t].y, ev[cj].y, a);
                    a = fmaf(xv[t].z, ev[cj].z, a);
                    a = fmaf(xv[t].w, ev[cj].w, a);
                    acc[t][cj] = a;
                }
            }
        }
        #pragma unroll
        for (int cj = 0; cj < 8; ++cj)
            #pragma unroll
            for (int t = 0; t < 4; ++t)
                if (acc[t][cj] > best_v[t]) { best_v[t] = acc[t][cj]; best_i[t] = c0 + cj; }
    }
    #pragma unroll
    for (int t = 0; t < 4; ++t) { red_v[i + 16 * t][j] = best_v[t]; red_i[i + 16 * t][j] = best_i[t]; }
    __syncthreads();
    if (tid < 64) {
        float bv = red_v[tid][0]; int bi = red_i[tid][0];
        #pragma unroll
        for (int jj = 1; jj < 16; ++jj) {
            const float v = red_v[tid][jj]; const int id = red_i[tid][jj];
            if (v > bv || (v == bv && id < bi)) { bv = v; bi = id; }
        }
        idx_lds[tid] = bi;
    }
    __syncthreads();
    {
        float* dst = out + (size_t)b * CC * HW + (size_t)h * WW + w;
        const float* erow = emb + (size_t)idx_lds[w] * DD;
        #pragma unroll
        for (int c = cs; c < CC; c += 4) {
            const float x = x_lds[w][c];
            const float q = erow[c];
            dst[(size_t)c * HW] = x + (q - x);
        }
    }
}

extern "C" void kernel_launch(void* const* d_in, const int* in_sizes, int n_in,
                              void* d_out, int out_size, void* d_ws, size_t ws_size,
                              hipStream_t stream) {
    const float* in  = (const float*)d_in[0];
    const float* emb = (const float*)d_in[1];
    float* out = (float*)d_out;
    char* ws = (char*)d_ws;

    float* ehalf = (float*)ws;                                        // 4 KiB
    const size_t OFF_EBT  = 4096;
    const size_t OFF_CNT  = OFF_EBT + (size_t)KK * DD * 2 * 2;        // +1 MiB
    const size_t OFF_LIST = OFF_CNT + 128;
    const size_t NEED     = OFF_LIST + (size_t)BB * HH * WW * 4;      // +256 KiB

    if (ws_size < NEED) {
        vq_enorm_kernel<<<KK / 4, 256, 0, stream>>>(emb, ehalf, (int*)ws);  // g_cnt unused
        vq_fallback_kernel<<<BB * HH, 256, 0, stream>>>(in, emb, ehalf, out);
        return;
    }
    unsigned short* ebt = (unsigned short*)(ws + OFF_EBT);
    int* g_cnt  = (int*)(ws + OFF_CNT);
    int* g_list = (int*)(ws + OFF_LIST);

    vq_enorm_kernel<<<KK / 4, 256, 0, stream>>>(emb, ehalf, g_cnt);
    vq_split_t_kernel<<<KK / 8, 256, 0, stream>>>(emb, ebt);
    vq_mfma_kernel<<<BB * HH, 256, 0, stream>>>(in, emb, ehalf, ebt, g_cnt, g_list, out);
    vq_rescue_kernel<<<256, 256, 0, stream>>>(in, emb, ehalf, g_cnt, g_list, out);
}

// Round 10
// 398.925 us; speedup vs baseline: 1.0150x; 1.0150x over previous
//
#include <hip/hip_runtime.h>

// VQ: B=16, C=D=256, H=64, W=64, K=1024
#define BB 16
#define CC 256
#define HH 64
#define WW 64
#define KK 1024
#define DD 256
#define HW (HH * WW)
#define TAU 0.0625f

typedef __attribute__((ext_vector_type(8))) short bf16x8;
typedef __attribute__((ext_vector_type(16))) float f32x16;

union Frag { bf16x8 v; unsigned int u[4]; };

// trunc-split 8 floats into bf16 hi/lo fragments (x = hi + lo + O(2^-16 x), Sterbenz-exact lo)
__device__ inline void split8r(const float4 a, const float4 b, Frag& hi, Frag& lo) {
    float f[8] = {a.x, a.y, a.z, a.w, b.x, b.y, b.z, b.w};
    #pragma unroll
    for (int p = 0; p < 4; ++p) {
        const unsigned int b0 = __float_as_uint(f[2 * p]), b1 = __float_as_uint(f[2 * p + 1]);
        const unsigned int h0 = b0 & 0xFFFF0000u, h1 = b1 & 0xFFFF0000u;
        const float r0 = f[2 * p]     - __uint_as_float(h0);
        const float r1 = f[2 * p + 1] - __uint_as_float(h1);
        hi.u[p] = (h0 >> 16) | h1;
        lo.u[p] = (__float_as_uint(r0) >> 16) | (__float_as_uint(r1) & 0xFFFF0000u);
    }
}

// ehalf[k] = 0.5||e_k||^2 (exact fp32); also zeroes the rescue counter.
__global__ __launch_bounds__(256) void vq_enorm_kernel(const float* __restrict__ e,
                                                       float* __restrict__ ehalf,
                                                       int* __restrict__ g_cnt) {
    if (blockIdx.x == 0 && threadIdx.x == 0) *g_cnt = 0;
    const int wave = threadIdx.x >> 6;
    const int lane = threadIdx.x & 63;
    const int k = blockIdx.x * 4 + wave;
    const float4 v = *reinterpret_cast<const float4*>(e + (size_t)k * DD + lane * 4);
    float s = v.x * v.x + v.y * v.y + v.z * v.z + v.w * v.w;
    #pragma unroll
    for (int off = 32; off; off >>= 1) s += __shfl_xor(s, off, 64);
    if (lane == 0) ehalf[k] = 0.5f * s;
}

// Split codebook into bf16 hi/lo, MFMA-fragment-linear (validated r9):
// elem off = ct*16384 + ks*1024 + term*512 + lane*8 + di,
// code = ct*32 + (lane&31), dim = ks*16 + (lane>>5)*8 + di.
__global__ __launch_bounds__(256) void vq_split_t_kernel(const float* __restrict__ e,
                                                         unsigned short* __restrict__ ebt) {
    const int tid = threadIdx.x;
    const int code = blockIdx.x * 8 + (tid >> 5);
    const int sub = tid & 31;
    const int ks = sub >> 1, lq = sub & 1;
    const int ct = code >> 5, lc = code & 31;
    const float* src = e + (size_t)code * DD + ks * 16 + lq * 8;
    Frag hi, lo;
    split8r(*reinterpret_cast<const float4*>(src),
            *reinterpret_cast<const float4*>(src + 4), hi, lo);
    unsigned short* dst = ebt + (size_t)ct * 16384 + ks * 1024 + (size_t)(lq * 32 + lc) * 8;
    *reinterpret_cast<bf16x8*>(dst)       = hi.v;   // term 0 (hi)
    *reinterpret_cast<bf16x8*>(dst + 512) = lo.v;   // term 1 (lo)
}

// Main: one block per (b,h) = 64 tokens x all 1024 codes.
// A (tokens) pre-split to bf16 hi/lo in LDS, ds_read_b128 per fragment use
// (low register pressure -> no spill). B streamed from L2 via ebt (r9-proven).
// 2 code-tiles per pass: 4 independent acc chains, A-read amortized 2x.
// No barriers / no inline asm in the K-loop.
__global__ __launch_bounds__(256, 2) void vq_mfma_kernel(
    const float* __restrict__ in, const float* __restrict__ emb,
    const float* __restrict__ ehalf, const unsigned short* __restrict__ ebt,
    int* __restrict__ g_cnt, int* __restrict__ g_list,
    float* __restrict__ out) {

    __shared__ unsigned short a_lds[32][64][16];   // [ks*2+term][token][16 k-elems] bf16, 64 KB
    __shared__ float eh_lds[KK];
    __shared__ float mv[64][2], m2l[64][2];
    __shared__ int   mi[64][2];
    __shared__ int   idx_lds[64];

    const int tid = threadIdx.x;
    const int bid = blockIdx.x;
    const int b = bid >> 6, h = bid & 63;
    const int w = tid & 63, cs = tid >> 6;

    // ---- stage A: load x (coalesced over w), split, write bf16 hi/lo to LDS ----
    {
        const float* src = in + (size_t)b * CC * HW + (size_t)h * WW + w;
        #pragma unroll
        for (int i = 0; i < 4; ++i) {
            const int ks = cs * 4 + i;
            float f[16];
            #pragma unroll
            for (int e = 0; e < 16; ++e) f[e] = src[(size_t)(ks * 16 + e) * HW];
            Frag h0, l0, h1, l1;
            split8r(make_float4(f[0], f[1], f[2], f[3]),
                    make_float4(f[4], f[5], f[6], f[7]), h0, l0);
            split8r(make_float4(f[8], f[9], f[10], f[11]),
                    make_float4(f[12], f[13], f[14], f[15]), h1, l1);
            *reinterpret_cast<bf16x8*>(&a_lds[ks * 2][w][0])     = h0.v;
            *reinterpret_cast<bf16x8*>(&a_lds[ks * 2][w][8])     = h1.v;
            *reinterpret_cast<bf16x8*>(&a_lds[ks * 2 + 1][w][0]) = l0.v;
            *reinterpret_cast<bf16x8*>(&a_lds[ks * 2 + 1][w][8]) = l1.v;
        }
        #pragma unroll
        for (int k = tid; k < KK; k += 256) eh_lds[k] = ehalf[k];
    }
    __syncthreads();

    const int lane = tid & 63;
    const int wv = tid >> 6;                 // 4 waves: (mg, ng)
    const int mg = wv >> 1, ng = wv & 1;
    const int lc = lane & 31, lq = lane >> 5;
    const int trow = mg * 32 + lc;

    float bestv[16], best2[16]; int besti[16];
    #pragma unroll
    for (int r = 0; r < 16; ++r) { bestv[r] = -3.4e38f; best2[r] = -3.4e38f; besti[r] = 0; }

    // ---- K-loop: 8 passes x 2 code-tiles; per ks: 2 ds_read(A) + 4 gload(B) + 6 MFMA ----
    #pragma unroll 1
    for (int ctj = 0; ctj < 8; ++ctj) {
        const int ct0 = ng * 16 + ctj * 2;
        const int ct1 = ct0 + 1;
        const unsigned short* bb0 = ebt + (size_t)ct0 * 16384 + (size_t)lane * 8;
        const unsigned short* bb1 = ebt + (size_t)ct1 * 16384 + (size_t)lane * 8;
        const int code0 = ct0 * 32 + lc;
        const int code1 = ct1 * 32 + lc;
        const float nh0 = -eh_lds[code0];
        const float nh1 = -eh_lds[code1];
        f32x16 ah0, al0, ah1, al1;
        #pragma unroll
        for (int r = 0; r < 16; ++r) { ah0[r] = nh0; al0[r] = 0.0f; ah1[r] = nh1; al1[r] = 0.0f; }
        #pragma unroll
        for (int ks = 0; ks < 16; ++ks) {
            const bf16x8 af_h = *reinterpret_cast<const bf16x8*>(&a_lds[ks * 2][trow][lq * 8]);
            const bf16x8 af_l = *reinterpret_cast<const bf16x8*>(&a_lds[ks * 2 + 1][trow][lq * 8]);
            const bf16x8 bh0 = *reinterpret_cast<const bf16x8*>(bb0 + ks * 1024);
            const bf16x8 bl0 = *reinterpret_cast<const bf16x8*>(bb0 + ks * 1024 + 512);
            const bf16x8 bh1 = *reinterpret_cast<const bf16x8*>(bb1 + ks * 1024);
            const bf16x8 bl1 = *reinterpret_cast<const bf16x8*>(bb1 + ks * 1024 + 512);
            ah0 = __builtin_amdgcn_mfma_f32_32x32x16_bf16(af_h, bh0, ah0, 0, 0, 0);
            ah1 = __builtin_amdgcn_mfma_f32_32x32x16_bf16(af_h, bh1, ah1, 0, 0, 0);
            al0 = __builtin_amdgcn_mfma_f32_32x32x16_bf16(af_l, bh0, al0, 0, 0, 0);
            al1 = __builtin_amdgcn_mfma_f32_32x32x16_bf16(af_l, bh1, al1, 0, 0, 0);
            ah0 = __builtin_amdgcn_mfma_f32_32x32x16_bf16(af_h, bl0, ah0, 0, 0, 0);
            ah1 = __builtin_amdgcn_mfma_f32_32x32x16_bf16(af_h, bl1, ah1, 0, 0, 0);
        }
        #pragma unroll
        for (int r = 0; r < 16; ++r) {
            const float v0 = ah0[r] + al0[r];
            if (v0 > bestv[r]) { best2[r] = bestv[r]; bestv[r] = v0; besti[r] = code0; }
            else if (v0 > best2[r]) best2[r] = v0;
            const float v1 = ah1[r] + al1[r];
            if (v1 > bestv[r]) { best2[r] = bestv[r]; bestv[r] = v1; besti[r] = code1; }
            else if (v1 > best2[r]) best2[r] = v1;
        }
    }

    // ---- butterfly across the 32 code-columns ----
    #pragma unroll
    for (int m = 1; m < 32; m <<= 1) {
        #pragma unroll
        for (int r = 0; r < 16; ++r) {
            const float ob = __shfl_xor(bestv[r], m, 64);
            const float o2 = __shfl_xor(best2[r], m, 64);
            const int   oi = __shfl_xor(besti[r], m, 64);
            if (ob > bestv[r] || (ob == bestv[r] && oi < besti[r])) {
                best2[r] = fmaxf(bestv[r], o2); bestv[r] = ob; besti[r] = oi;
            } else {
                best2[r] = fmaxf(best2[r], ob);
            }
        }
    }
    if (lc == 0) {
        #pragma unroll
        for (int r = 0; r < 16; ++r) {
            const int row = mg * 32 + (r & 3) + 8 * (r >> 2) + 4 * lq;  // C/D row map (m74/m101)
            mv[row][ng] = bestv[r]; m2l[row][ng] = best2[r]; mi[row][ng] = besti[r];
        }
    }
    __syncthreads();

    // ---- merge ng halves per token; flag small margins into compact rescue list ----
    if (tid < 64) {
        const float v0 = mv[tid][0], s0 = m2l[tid][0]; const int i0 = mi[tid][0];
        const float v1 = mv[tid][1], s1 = m2l[tid][1]; const int i1 = mi[tid][1];
        float fb, f2; int fi;
        if (v1 > v0 || (v1 == v0 && i1 < i0)) { fb = v1; fi = i1; f2 = fmaxf(v0, s1); }
        else { fb = v0; fi = i0; f2 = fmaxf(s0, v1); }
        idx_lds[tid] = fi;
        if (fb - f2 < TAU) {
            const int p = atomicAdd(g_cnt, 1);
            g_list[p] = (bid << 6) + tid;
        }
    }
    __syncthreads();

    // ---- epilogue: out = x + (q - x), x re-read from global (coalesced, r8-validated) ----
    {
        const float* srcx = in + (size_t)b * CC * HW + (size_t)h * WW + w;
        float* dst = out + (size_t)b * CC * HW + (size_t)h * WW + w;
        const float* erow = emb + (size_t)idx_lds[w] * DD;
        #pragma unroll
        for (int c = cs; c < CC; c += 4) {
            const float x = srcx[(size_t)c * HW];
            const float q = erow[c];
            dst[(size_t)c * HW] = x + (q - x);
        }
    }
}

// Rescue: flagged tokens recomputed exactly in fp32 (validated r8/r9).
__global__ __launch_bounds__(256) void vq_rescue_kernel(
    const float* __restrict__ in, const float* __restrict__ emb,
    const float* __restrict__ ehalf, const int* __restrict__ g_cnt,
    const int* __restrict__ g_list, float* __restrict__ out) {

    __shared__ float xs[DD];
    __shared__ float rv[4]; __shared__ int ri[4];
    __shared__ int fin;

    const int tid = threadIdx.x;
    const int n = *g_cnt;
    for (int li = blockIdx.x; li < n; li += (int)gridDim.x) {
        const int tok = g_list[li];
        const int b = tok >> 12, h = (tok >> 6) & 63, w = tok & 63;
        xs[tid] = in[(size_t)(b * CC + tid) * HW + h * WW + w];
        __syncthreads();
        float best = -3.4e38f; int bidx = 0;
        #pragma unroll
        for (int cc = 0; cc < 4; ++cc) {
            const int code = tid * 4 + cc;
            float sc = -ehalf[code];
            const float* er = emb + (size_t)code * DD;
            for (int d = 0; d < DD; d += 4) {
                sc = fmaf(xs[d + 0], er[d + 0], sc);
                sc = fmaf(xs[d + 1], er[d + 1], sc);
                sc = fmaf(xs[d + 2], er[d + 2], sc);
                sc = fmaf(xs[d + 3], er[d + 3], sc);
            }
            if (sc > best) { best = sc; bidx = code; }
        }
        #pragma unroll
        for (int m = 1; m < 64; m <<= 1) {
            const float ov = __shfl_xor(best, m, 64);
            const int   oi = __shfl_xor(bidx, m, 64);
            if (ov > best || (ov == best && oi < bidx)) { best = ov; bidx = oi; }
        }
        if ((tid & 63) == 0) { rv[tid >> 6] = best; ri[tid >> 6] = bidx; }
        __syncthreads();
        if (tid == 0) {
            float fb = rv[0]; int fi2 = ri[0];
            #pragma unroll
            for (int q2 = 1; q2 < 4; ++q2)
                if (rv[q2] > fb || (rv[q2] == fb && ri[q2] < fi2)) { fb = rv[q2]; fi2 = ri[q2]; }
            fin = fi2;
        }
        __syncthreads();
        const int fid = fin;
        const float xv = xs[tid];
        const float qv = emb[(size_t)fid * DD + tid];
        out[(size_t)(b * CC + tid) * HW + h * WW + w] = xv + (qv - xv);
        __syncthreads();
    }
}

// Fallback (validated fp32 VALU path) if ws is too small.
__global__ __launch_bounds__(256) void vq_fallback_kernel(
    const float* __restrict__ in, const float* __restrict__ emb,
    const float* __restrict__ ehalf, float* __restrict__ out) {

    __shared__ float x_lds[64][260];
    __shared__ float red_v[64][16];
    __shared__ int   red_i[64][16];
    __shared__ int   idx_lds[64];

    const int tid = threadIdx.x;
    const int bid = blockIdx.x;
    const int b = bid >> 6, h = bid & 63;
    const int w = tid & 63, cs = tid >> 6;
    {
        const float* src = in + (size_t)b * CC * HW + (size_t)h * WW + w;
        #pragma unroll
        for (int c = cs; c < CC; c += 4) x_lds[w][c] = src[(size_t)c * HW];
    }
    __syncthreads();
    const int i = tid & 15;
    const int j = tid >> 4;
    float best_v[4]; int best_i[4];
    #pragma unroll
    for (int t = 0; t < 4; ++t) { best_v[t] = -3.4e38f; best_i[t] = 0; }
    for (int chunk = 0; chunk < KK; chunk += 128) {
        const int c0 = chunk + j * 8;
        const float* e0 = emb + (size_t)c0 * DD;
        float acc[4][8];
        #pragma unroll
        for (int cj = 0; cj < 8; ++cj) {
            const float nh = -ehalf[c0 + cj];
            #pragma unroll
            for (int t = 0; t < 4; ++t) acc[t][cj] = nh;
        }
        #pragma unroll 2
        for (int d = 0; d < DD; d += 4) {
            float4 xv[4], ev[8];
            #pragma unroll
            for (int t = 0; t < 4; ++t)
                xv[t] = *reinterpret_cast<const float4*>(&x_lds[i + 16 * t][d]);
            #pragma unroll
            for (int cj = 0; cj < 8; ++cj)
                ev[cj] = *reinterpret_cast<const float4*>(e0 + (size_t)cj * DD + d);
            #pragma unroll
            for (int t = 0; t < 4; ++t) {
                #pragma unroll
                for (int cj = 0; cj < 8; ++cj) {
                    float a = acc[t][cj];
                    a = fmaf(xv[t].x, ev[cj].x, a);
                    a = fmaf(xv[t].y, ev[cj].y, a);
                    a = fmaf(xv[t].z, ev[cj].z, a);
                    a = fmaf(xv[t].w, ev[cj].w, a);
                    acc[t][cj] = a;
                }
            }
        }
        #pragma unroll
        for (int cj = 0; cj < 8; ++cj)
            #pragma unroll
            for (int t = 0; t < 4; ++t)
                if (acc[t][cj] > best_v[t]) { best_v[t] = acc[t][cj]; best_i[t] = c0 + cj; }
    }
    #pragma unroll
    for (int t = 0; t < 4; ++t) { red_v[i + 16 * t][j] = best_v[t]; red_i[i + 16 * t][j] = best_i[t]; }
    __syncthreads();
    if (tid < 64) {
        float bv = red_v[tid][0]; int bi = red_i[tid][0];
        #pragma unroll
        for (int jj = 1; jj < 16; ++jj) {
            const float v = red_v[tid][jj]; const int id = red_i[tid][jj];
            if (v > bv || (v == bv && id < bi)) { bv = v; bi = id; }
        }
        idx_lds[tid] = bi;
    }
    __syncthreads();
    {
        float* dst = out + (size_t)b * CC * HW + (size_t)h * WW + w;
        const float* erow = emb + (size_t)idx_lds[w] * DD;
        #pragma unroll
        for (int c = cs; c < CC; c += 4) {
            const float x = x_lds[w][c];
            const float q = erow[c];
            dst[(size_t)c * HW] = x + (q - x);
        }
    }
}

extern "C" void kernel_launch(void* const* d_in, const int* in_sizes, int n_in,
                              void* d_out, int out_size, void* d_ws, size_t ws_size,
                              hipStream_t stream) {
    const float* in  = (const float*)d_in[0];
    const float* emb = (const float*)d_in[1];
    float* out = (float*)d_out;
    char* ws = (char*)d_ws;

    float* ehalf = (float*)ws;                                        // 4 KiB
    const size_t OFF_EBT  = 4096;
    const size_t OFF_CNT  = OFF_EBT + (size_t)KK * DD * 2 * 2;        // +1 MiB
    const size_t OFF_LIST = OFF_CNT + 128;
    const size_t NEED     = OFF_LIST + (size_t)BB * HH * WW * 4;      // +256 KiB

    if (ws_size < NEED) {
        vq_enorm_kernel<<<KK / 4, 256, 0, stream>>>(emb, ehalf, (int*)ws);  // g_cnt unused
        vq_fallback_kernel<<<BB * HH, 256, 0, stream>>>(in, emb, ehalf, out);
        return;
    }
    unsigned short* ebt = (unsigned short*)(ws + OFF_EBT);
    int* g_cnt  = (int*)(ws + OFF_CNT);
    int* g_list = (int*)(ws + OFF_LIST);

    vq_enorm_kernel<<<KK / 4, 256, 0, stream>>>(emb, ehalf, g_cnt);
    vq_split_t_kernel<<<KK / 8, 256, 0, stream>>>(emb, ebt);
    vq_mfma_kernel<<<BB * HH, 256, 0, stream>>>(in, emb, ehalf, ebt, g_cnt, g_list, out);
    vq_rescue_kernel<<<256, 256, 0, stream>>>(in, emb, ehalf, g_cnt, g_list, out);
}